// Round 2
// baseline (4510.821 us; speedup 1.0000x reference)
//
#include <hip/hip_runtime.h>
#include <cstddef>
#include <cmath>

// Problem constants
#define B_    64
#define L_    128
#define V_    20000
#define D_    300
#define H_    256
#define NE_   34
#define NA_   36
#define M_    8192      // L_*B_
#define KP_   304       // D_ padded to multiple of 16
#define NPROJ_ 2048     // 2 dirs * 4H
#define K2_   512       // 2H
#define NCAT_ 128       // 36 (part_j) + 36 (part_i) + 34 (logit_h) padded to 128

__device__ __forceinline__ float sigmoidf_(float x) { return 1.0f / (1.0f + expf(-x)); }

// ---------------------------------------------------------------------------
// K1: gather embeddings into X (M_ x KP_), zero-padded K tail. X[m][k], m = l*B_+b
__global__ __launch_bounds__(256) void k_gather(const float* __restrict__ emb,
                                                const int* __restrict__ ids,
                                                float* __restrict__ X) {
    int idx = blockIdx.x * 256 + threadIdx.x;
    if (idx >= M_ * KP_) return;
    int m = idx / KP_, k = idx - m * KP_;
    int l = m >> 6, b = m & 63;
    float v = 0.f;
    if (k < D_) {
        int tok = ids[b * L_ + l];
        v = emb[(size_t)tok * D_ + k];
    }
    X[idx] = v;
}

// K2: transposed input-proj weights Wt_ih (KP_ x NPROJ_) + combined bias
__global__ __launch_bounds__(256) void k_prep_wih(const float* __restrict__ Wf,
                                                  const float* __restrict__ Wb,
                                                  const float* __restrict__ bihf,
                                                  const float* __restrict__ bhhf,
                                                  const float* __restrict__ bihb,
                                                  const float* __restrict__ bhhb,
                                                  float* __restrict__ Wt,
                                                  float* __restrict__ bias) {
    int idx = blockIdx.x * 256 + threadIdx.x;
    if (idx >= KP_ * NPROJ_) return;
    int k = idx / NPROJ_, n = idx - k * NPROJ_;
    int dir = n >> 10, g = n & 1023;
    float v = 0.f;
    if (k < D_) v = dir ? Wb[g * D_ + k] : Wf[g * D_ + k];
    Wt[idx] = v;
    if (k == 0) bias[n] = dir ? (bihb[g] + bhhb[g]) : (bihf[g] + bhhf[g]);
}

// K4: combined head weights Wcat (K2_ x NCAT_)
__global__ __launch_bounds__(256) void k_prep_wcat(const float* __restrict__ Warg,
                                                   const float* __restrict__ Wev,
                                                   const float* __restrict__ barg,
                                                   const float* __restrict__ bev,
                                                   float* __restrict__ Wcat,
                                                   float* __restrict__ bias) {
    int idx = blockIdx.x * 256 + threadIdx.x;
    if (idx >= K2_ * NCAT_) return;
    int k = idx >> 7, n = idx & 127;
    float v = 0.f;
    if (n < 36)       v = Warg[n * 1024 + k];
    else if (n < 72)  v = Warg[(n - 36) * 1024 + 512 + k];
    else if (n < 106) v = Wev[(n - 72) * 545 + k];
    Wcat[idx] = v;
    if (k == 0) {
        float bv = 0.f;
        if (n >= 36 && n < 72)       bv = barg[n - 36];
        else if (n >= 72 && n < 106) bv = bev[n - 72];
        bias[n] = bv;
    }
}

// ---------------------------------------------------------------------------
// Generic fp32 tiled GEMM: C (MxN) = A (MxK) * Bm (KxN) + bias[n]
template <int K>
__global__ __launch_bounds__(256) void k_gemm(const float* __restrict__ A,
                                              const float* __restrict__ Bm,
                                              const float* __restrict__ bias,
                                              float* __restrict__ C, int N) {
    __shared__ float As[16][64];
    __shared__ float Bs[16][64];
    const int tid = threadIdx.x;
    const int m0 = blockIdx.x * 64, n0 = blockIdx.y * 64;
    const int tx = tid & 15, ty = tid >> 4;
    const int a_m = tid >> 2;
    const int a_k = (tid & 3) << 2;
    const int b_k = tid >> 4;
    const int b_n = (tid & 15) << 2;

    float acc[4][4] = {};
    for (int k0 = 0; k0 < K; k0 += 16) {
        float4 av = *(const float4*)&A[(size_t)(m0 + a_m) * K + k0 + a_k];
        float4 bv = *(const float4*)&Bm[(size_t)(k0 + b_k) * N + n0 + b_n];
        __syncthreads();
        As[a_k][a_m] = av.x; As[a_k + 1][a_m] = av.y;
        As[a_k + 2][a_m] = av.z; As[a_k + 3][a_m] = av.w;
        *(float4*)&Bs[b_k][b_n] = bv;
        __syncthreads();
#pragma unroll
        for (int kk = 0; kk < 16; kk++) {
            float4 a4 = *(const float4*)&As[kk][ty << 2];
            float4 b4 = *(const float4*)&Bs[kk][tx << 2];
            float ar[4] = {a4.x, a4.y, a4.z, a4.w};
            float br[4] = {b4.x, b4.y, b4.z, b4.w};
#pragma unroll
            for (int i = 0; i < 4; i++)
#pragma unroll
                for (int j = 0; j < 4; j++) acc[i][j] += ar[i] * br[j];
        }
    }
    float4 bb = *(const float4*)&bias[n0 + (tx << 2)];
#pragma unroll
    for (int i = 0; i < 4; i++) {
        int m = m0 + (ty << 2) + i;
        float4 o;
        o.x = acc[i][0] + bb.x; o.y = acc[i][1] + bb.y;
        o.z = acc[i][2] + bb.z; o.w = acc[i][3] + bb.w;
        *(float4*)&C[(size_t)m * N + n0 + (tx << 2)] = o;
    }
}

// ---------------------------------------------------------------------------
// BiLSTM v2: W_hh held in VGPRs, gate-sliced across 8 cooperating blocks.
// grid = 256 blocks: blk = dir*128 + bg*8 + s
//   dir: direction, bg: batch-group (4 rows), s: gate slice (32 units)
// Block thread map: tid = gg*8 + ks; gg in [0,32) owns gates 4gg..4gg+3 (local),
// ks in [0,8) owns k-range [32ks, 32ks+32).
// Per-step h exchange through global hx (double-buffered) + per-group counter.
__global__ __launch_bounds__(256, 2) void k_lstm2(const float* __restrict__ pre,
                                                  const float* __restrict__ Whhf,
                                                  const float* __restrict__ Whhb,
                                                  float* __restrict__ hs,
                                                  float* hx, int* cnt) {
    const int blk = blockIdx.x;
    const int dir = blk >> 7;
    const int bg  = (blk >> 3) & 15;
    const int s   = blk & 7;
    const int grp = dir * 16 + bg;           // 32 groups, 8 blocks each
    const int b0  = bg * 4;
    const int tid = threadIdx.x;
    const int gg  = tid >> 3;                // 0..31
    const int ks  = tid & 7;                 // 0..7
    const float* W = dir ? Whhb : Whhf;      // [1024][256] row-major

    __shared__ float4 h4[4][64];             // [row][rotated k-quad]
    __shared__ float  gbuf[4][129];          // [row][local gate] pre + acc

    // --- load W slice into registers: Wr[j][q] = W[grow(4gg+j)][32ks+4q .. +3]
    float4 Wr[4][8];
#pragma unroll
    for (int j = 0; j < 4; j++) {
        int lg = 4 * gg + j;                           // local gate 0..127
        int grow = ((lg >> 5) << 8) + s * 32 + (lg & 31);  // global gate row
        const float* wrow = W + (size_t)grow * 256 + 32 * ks;
#pragma unroll
        for (int q = 0; q < 8; q++) Wr[j][q] = *(const float4*)(wrow + 4 * q);
    }

    // c-state: threads tid<128 own (unit ul, row rr)
    const int ul = tid >> 2, rr = tid & 3;
    float c = 0.f;

    // zero h_lds (h(-1) = 0)
    h4[tid >> 6][tid & 63] = float4{0.f, 0.f, 0.f, 0.f};
    __syncthreads();

    const int u_glob = s * 32 + ul;
    for (int step = 0; step < L_; step++) {
        const int l = dir ? (L_ - 1 - step) : step;

        // prefetch pre for this step: values v=tid and v=tid+256 over (r*128+lg)
        const int plg = tid & 127;
        const int pr0 = tid >> 7, pr1 = 2 + (tid >> 7);
        const int pgg = ((plg >> 5) << 8) + s * 32 + (plg & 31);
        float pv0 = pre[(size_t)(l * 64 + b0 + pr0) * NPROJ_ + dir * 1024 + pgg];
        float pv1 = pre[(size_t)(l * 64 + b0 + pr1) * NPROJ_ + dir * 1024 + pgg];

        if (step > 0) {
            if (tid == 0) {
                while (__hip_atomic_load(&cnt[grp], __ATOMIC_ACQUIRE,
                                         __HIP_MEMORY_SCOPE_AGENT) < 8 * step) {
                    __builtin_amdgcn_s_sleep(1);
                }
            }
            __syncthreads();
            // read h(step-1) from hx and scatter into rotated LDS layout
            const int r = tid >> 6, kq = tid & 63;
            const float* src = hx + ((size_t)(((step - 1) & 1) * 32 + grp)) * 1024
                                  + r * 256 + 4 * kq;
            float x0 = __hip_atomic_load(src + 0, __ATOMIC_RELAXED, __HIP_MEMORY_SCOPE_AGENT);
            float x1 = __hip_atomic_load(src + 1, __ATOMIC_RELAXED, __HIP_MEMORY_SCOPE_AGENT);
            float x2 = __hip_atomic_load(src + 2, __ATOMIC_RELAXED, __HIP_MEMORY_SCOPE_AGENT);
            float x3 = __hip_atomic_load(src + 3, __ATOMIC_RELAXED, __HIP_MEMORY_SCOPE_AGENT);
            int rot = ((kq & 7) << 3) | (kq >> 3);
            h4[r][rot] = float4{x0, x1, x2, x3};
        }
        gbuf[pr0][plg] = pv0;
        gbuf[pr1][plg] = pv1;
        __syncthreads();

        // --- compute partial gates: acc[j][r] over k in [32ks, 32ks+32)
        float acc[4][4] = {};
#pragma unroll
        for (int q = 0; q < 8; q++) {
#pragma unroll
            for (int r = 0; r < 4; r++) {
                float4 h = h4[r][(q << 3) | ks];   // conflict-free: bank=4ks, gg broadcast
#pragma unroll
                for (int j = 0; j < 4; j++) {
                    acc[j][r] += Wr[j][q].x * h.x + Wr[j][q].y * h.y
                               + Wr[j][q].z * h.z + Wr[j][q].w * h.w;
                }
            }
        }
        // --- reduce over the 8 k-slices (lanes differing in low 3 bits)
#pragma unroll
        for (int j = 0; j < 4; j++)
#pragma unroll
            for (int r = 0; r < 4; r++) {
                float v = acc[j][r];
                v += __shfl_xor(v, 1, 64);
                v += __shfl_xor(v, 2, 64);
                v += __shfl_xor(v, 4, 64);
                if (ks == 0) gbuf[r][4 * gg + j] += v;
            }
        __syncthreads();

        // --- LSTM cell update for (ul, rr), write h everywhere needed
        if (tid < 128) {
            float ig = sigmoidf_(gbuf[rr][ul]);
            float fg = sigmoidf_(gbuf[rr][32 + ul]);
            float gz = tanhf(gbuf[rr][64 + ul]);
            float og = sigmoidf_(gbuf[rr][96 + ul]);
            c = fg * c + ig * gz;
            float h = og * tanhf(c);
            hs[(size_t)(l * 64 + b0 + rr) * 512 + dir * 256 + u_glob] = h;
            hx[((size_t)((step & 1) * 32 + grp)) * 1024 + rr * 256 + u_glob] = h;
            __threadfence();
        }
        __syncthreads();
        if (tid == 0)
            __hip_atomic_fetch_add(&cnt[grp], 1, __ATOMIC_RELEASE, __HIP_MEMORY_SCOPE_AGENT);
    }
}

// ---------------------------------------------------------------------------
// Event head sequential scan. One block (1 wave) per batch row.
__global__ __launch_bounds__(64) void k_event(const float* __restrict__ part,
                                              const float* __restrict__ Wev,
                                              float* __restrict__ out_ev) {
    const int b = blockIdx.x;
    const int e = threadIdx.x;
    __shared__ float sg[33];
    if (e < 33) sg[e] = 0.f;
    float wreg[33];
    if (e < NE_) {
#pragma unroll
        for (int j = 0; j < 33; j++) wreg[j] = Wev[e * 545 + 512 + j];
    }
    __syncthreads();
    for (int l = 0; l < L_; l++) {
        const int m = l * B_ + b;
        float v = -3.0e38f;
        if (e < NE_) {
            v = part[(size_t)m * NCAT_ + 72 + e];
#pragma unroll
            for (int j = 0; j < 33; j++) v += wreg[j] * sg[j];
            out_ev[((size_t)b * L_ + l) * NE_ + e] = v;
        }
        float bv = v;
        int bi = e;
#pragma unroll
        for (int off = 32; off > 0; off >>= 1) {
            float ov = __shfl_xor(bv, off, 64);
            int oi = __shfl_xor(bi, off, 64);
            if (ov > bv || (ov == bv && oi < bi)) { bv = ov; bi = oi; }
        }
        __syncthreads();
        if (bi > 0 && e == bi - 1) sg[e] = 1.f;
        __syncthreads();
    }
}

// ---------------------------------------------------------------------------
// Argument logits broadcast: out[b][i][j][a] = part_i[b][i][a] + part_j[b][j][a]
__global__ __launch_bounds__(256) void k_arg(const float* __restrict__ part,
                                             float* __restrict__ out) {
    const int blk = blockIdx.x;            // b*L_ + i
    const int b = blk >> 7, i = blk & 127;
    __shared__ float pj[L_ * NA_];
    __shared__ float pi_s[NA_];
    const int tid = threadIdx.x;
    if (tid < NA_) pi_s[tid] = part[(size_t)(i * B_ + b) * NCAT_ + 36 + tid];
    for (int idx = tid; idx < L_ * NA_; idx += 256) {
        int j = idx / NA_, a = idx - j * NA_;
        pj[idx] = part[(size_t)(j * B_ + b) * NCAT_ + a];
    }
    __syncthreads();
    float* o = out + (size_t)blk * (L_ * NA_);
    for (int idx = tid; idx < L_ * NA_; idx += 256) {
        int a = idx % NA_;
        o[idx] = pi_s[a] + pj[idx];
    }
}

// ---------------------------------------------------------------------------
extern "C" void kernel_launch(void* const* d_in, const int* in_sizes, int n_in,
                              void* d_out, int out_size, void* d_ws, size_t ws_size,
                              hipStream_t stream) {
    const float* emb  = (const float*)d_in[0];
    const float* Wihf = (const float*)d_in[1];
    const float* Whhf = (const float*)d_in[2];
    const float* bihf = (const float*)d_in[3];
    const float* bhhf = (const float*)d_in[4];
    const float* Wihb = (const float*)d_in[5];
    const float* Whhb = (const float*)d_in[6];
    const float* bihb = (const float*)d_in[7];
    const float* bhhb = (const float*)d_in[8];
    const float* Wev  = (const float*)d_in[9];
    const float* bev  = (const float*)d_in[10];
    const float* Warg = (const float*)d_in[11];
    const float* barg = (const float*)d_in[12];
    const int*   ids  = (const int*)d_in[13];
    float* out = (float*)d_out;
    float* ws  = (float*)d_ws;

    // Workspace layout (floats). X region reused for `part`.
    float* X       = ws;                 // 8192*304
    float* part    = ws;                 // 8192*128 (reuse)
    float* Wt_ih   = ws + 2490368;       // 304*2048
    float* bias_p  = ws + 3112960;       // 2048
    int*   cnt     = (int*)(ws + 3115008);  // 32 ints (old Wt_hh slot)
    float* hx      = ws + 3115072;       // 2*32*1024 = 65536
    float* Wcat    = ws + 3639296;       // 512*128
    float* bias_c  = ws + 3704832;       // 128
    float* pre_all = ws + 3704960;       // 8192*2048
    float* hsbuf   = ws + 20482176;      // 8192*512

    hipMemsetAsync(cnt, 0, 32 * sizeof(int), stream);
    k_gather<<<(M_ * KP_) / 256, 256, 0, stream>>>(emb, ids, X);
    k_prep_wih<<<(KP_ * NPROJ_) / 256, 256, 0, stream>>>(Wihf, Wihb, bihf, bhhf, bihb, bhhb, Wt_ih, bias_p);
    k_prep_wcat<<<(K2_ * NCAT_) / 256, 256, 0, stream>>>(Warg, Wev, barg, bev, Wcat, bias_c);

    k_gemm<KP_><<<dim3(M_ / 64, NPROJ_ / 64), 256, 0, stream>>>(X, Wt_ih, bias_p, pre_all, NPROJ_);
    k_lstm2<<<256, 256, 0, stream>>>(pre_all, Whhf, Whhb, hsbuf, hx, cnt);
    k_gemm<K2_><<<dim3(M_ / 64, NCAT_ / 64), 256, 0, stream>>>(hsbuf, Wcat, bias_c, part, NCAT_);
    k_event<<<B_, 64, 0, stream>>>(part, Wev, out);
    k_arg<<<B_ * L_, 256, 0, stream>>>(part, out + (size_t)B_ * L_ * NE_);
}

// Round 3
// 1142.784 us; speedup vs baseline: 3.9472x; 3.9472x over previous
//
#include <hip/hip_runtime.h>
#include <cstddef>
#include <cmath>

// Problem constants
#define B_    64
#define L_    128
#define V_    20000
#define D_    300
#define H_    256
#define NE_   34
#define NA_   36
#define M_    8192      // L_*B_
#define KP_   304       // D_ padded to multiple of 16
#define NPROJ_ 2048     // 2 dirs * 4H
#define K2_   512       // 2H
#define NCAT_ 128       // 36 (part_j) + 36 (part_i) + 34 (logit_h) padded to 128

__device__ __forceinline__ float sigmoidf_(float x) { return 1.0f / (1.0f + expf(-x)); }

typedef __attribute__((ext_vector_type(2))) _Float16 half2_;

__device__ __forceinline__ half2_ u2h(unsigned u) {
    union { unsigned u; half2_ h; } c; c.u = u; return c.h;
}
__device__ __forceinline__ unsigned packh2(float a, float b) {
    union { half2_ h; unsigned u; } c;
    c.h = half2_{(_Float16)a, (_Float16)b};
    return c.u;
}

#if __has_builtin(__builtin_amdgcn_fdot2)
__device__ __forceinline__ float fdot2_(half2_ a, half2_ b, float c) {
    return __builtin_amdgcn_fdot2(a, b, c, false);
}
#else
__device__ __forceinline__ float fdot2_(half2_ a, half2_ b, float c) {
    return c + (float)a.x * (float)b.x + (float)a.y * (float)b.y;
}
#endif

// ---------------------------------------------------------------------------
// K1: gather embeddings into X (M_ x KP_), zero-padded K tail. X[m][k], m = l*B_+b
__global__ __launch_bounds__(256) void k_gather(const float* __restrict__ emb,
                                                const int* __restrict__ ids,
                                                float* __restrict__ X) {
    int idx = blockIdx.x * 256 + threadIdx.x;
    if (idx >= M_ * KP_) return;
    int m = idx / KP_, k = idx - m * KP_;
    int l = m >> 6, b = m & 63;
    float v = 0.f;
    if (k < D_) {
        int tok = ids[b * L_ + l];
        v = emb[(size_t)tok * D_ + k];
    }
    X[idx] = v;
}

// K2: transposed input-proj weights Wt_ih (KP_ x NPROJ_) + combined bias
__global__ __launch_bounds__(256) void k_prep_wih(const float* __restrict__ Wf,
                                                  const float* __restrict__ Wb,
                                                  const float* __restrict__ bihf,
                                                  const float* __restrict__ bhhf,
                                                  const float* __restrict__ bihb,
                                                  const float* __restrict__ bhhb,
                                                  float* __restrict__ Wt,
                                                  float* __restrict__ bias) {
    int idx = blockIdx.x * 256 + threadIdx.x;
    if (idx >= KP_ * NPROJ_) return;
    int k = idx / NPROJ_, n = idx - k * NPROJ_;
    int dir = n >> 10, g = n & 1023;
    float v = 0.f;
    if (k < D_) v = dir ? Wb[g * D_ + k] : Wf[g * D_ + k];
    Wt[idx] = v;
    if (k == 0) bias[n] = dir ? (bihb[g] + bhhb[g]) : (bihf[g] + bhhf[g]);
}

// K3: pack W_hh to fp16 half2, k-major: Wp[dir][kp][g] = (W[g][2kp], W[g][2kp+1])
__global__ __launch_bounds__(256) void k_prep_whh16(const float* __restrict__ Wf,
                                                    const float* __restrict__ Wb,
                                                    unsigned* __restrict__ Wp) {
    int idx = blockIdx.x * 256 + threadIdx.x;       // 2*128*1024
    if (idx >= 2 * 128 * 1024) return;
    int dir = idx >> 17, r = idx & 131071;
    int kp = r >> 10, g = r & 1023;
    const float* W = dir ? Wb : Wf;
    Wp[idx] = packh2(W[g * H_ + 2 * kp], W[g * H_ + 2 * kp + 1]);
}

// K4: combined head weights Wcat (K2_ x NCAT_)
__global__ __launch_bounds__(256) void k_prep_wcat(const float* __restrict__ Warg,
                                                   const float* __restrict__ Wev,
                                                   const float* __restrict__ barg,
                                                   const float* __restrict__ bev,
                                                   float* __restrict__ Wcat,
                                                   float* __restrict__ bias) {
    int idx = blockIdx.x * 256 + threadIdx.x;
    if (idx >= K2_ * NCAT_) return;
    int k = idx >> 7, n = idx & 127;
    float v = 0.f;
    if (n < 36)       v = Warg[n * 1024 + k];
    else if (n < 72)  v = Warg[(n - 36) * 1024 + 512 + k];
    else if (n < 106) v = Wev[(n - 72) * 545 + k];
    Wcat[idx] = v;
    if (k == 0) {
        float bv = 0.f;
        if (n >= 36 && n < 72)       bv = barg[n - 36];
        else if (n >= 72 && n < 106) bv = bev[n - 72];
        bias[n] = bv;
    }
}

// ---------------------------------------------------------------------------
// Generic fp32 tiled GEMM: C (MxN) = A (MxK) * Bm (KxN) + bias[n]
template <int K>
__global__ __launch_bounds__(256) void k_gemm(const float* __restrict__ A,
                                              const float* __restrict__ Bm,
                                              const float* __restrict__ bias,
                                              float* __restrict__ C, int N) {
    __shared__ float As[16][64];
    __shared__ float Bs[16][64];
    const int tid = threadIdx.x;
    const int m0 = blockIdx.x * 64, n0 = blockIdx.y * 64;
    const int tx = tid & 15, ty = tid >> 4;
    const int a_m = tid >> 2;
    const int a_k = (tid & 3) << 2;
    const int b_k = tid >> 4;
    const int b_n = (tid & 15) << 2;

    float acc[4][4] = {};
    for (int k0 = 0; k0 < K; k0 += 16) {
        float4 av = *(const float4*)&A[(size_t)(m0 + a_m) * K + k0 + a_k];
        float4 bv = *(const float4*)&Bm[(size_t)(k0 + b_k) * N + n0 + b_n];
        __syncthreads();
        As[a_k][a_m] = av.x; As[a_k + 1][a_m] = av.y;
        As[a_k + 2][a_m] = av.z; As[a_k + 3][a_m] = av.w;
        *(float4*)&Bs[b_k][b_n] = bv;
        __syncthreads();
#pragma unroll
        for (int kk = 0; kk < 16; kk++) {
            float4 a4 = *(const float4*)&As[kk][ty << 2];
            float4 b4 = *(const float4*)&Bs[kk][tx << 2];
            float ar[4] = {a4.x, a4.y, a4.z, a4.w};
            float br[4] = {b4.x, b4.y, b4.z, b4.w};
#pragma unroll
            for (int i = 0; i < 4; i++)
#pragma unroll
                for (int j = 0; j < 4; j++) acc[i][j] += ar[i] * br[j];
        }
    }
    float4 bb = *(const float4*)&bias[n0 + (tx << 2)];
#pragma unroll
    for (int i = 0; i < 4; i++) {
        int m = m0 + (ty << 2) + i;
        float4 o;
        o.x = acc[i][0] + bb.x; o.y = acc[i][1] + bb.y;
        o.z = acc[i][2] + bb.z; o.w = acc[i][3] + bb.w;
        *(float4*)&C[(size_t)m * N + n0 + (tx << 2)] = o;
    }
}

// ---------------------------------------------------------------------------
// BiLSTM v3: round-1 structure (64 independent blocks, dir x 2 batch rows),
// W_hh streamed from L2 as packed fp16 (half the bytes of round 1), fp32
// accumulate via v_dot2_f32_f16. h recurrence carried as packed half2 in LDS;
// hs output written in fp32 (pre-rounding).
// Thread t computes gates 4t..4t+3 for both rows, then owns hidden unit t.
__global__ __launch_bounds__(256) void k_lstm3(const float* __restrict__ pre,
                                               const unsigned* __restrict__ Wp,
                                               float* __restrict__ hs) {
    const int blk = blockIdx.x;
    const int dir = blk >> 5;
    const int b0 = (blk & 31) << 1;
    const int t = threadIdx.x;
    const unsigned* Wd = Wp + (size_t)dir * (128 * 1024);

    __shared__ unsigned h2s[2][128];   // packed half2 h-state per row
    __shared__ float gbuf[2][4 * H_];  // staged gates
    __shared__ float hf[2][H_];        // fp32 h scratch for packing

    float c0 = 0.f, c1 = 0.f;
    if (t < 128) { h2s[0][t] = 0u; h2s[1][t] = 0u; }
    __syncthreads();

    for (int step = 0; step < L_; step++) {
        const int l = dir ? (L_ - 1 - step) : step;
        const float* p0 = pre + (size_t)(l * B_ + b0) * NPROJ_ + dir * 1024 + (t << 2);
        float4 a0 = *(const float4*)p0;
        float4 a1 = *(const float4*)(p0 + NPROJ_);

#pragma unroll 16
        for (int kp = 0; kp < 128; kp++) {
            uint4 w = *(const uint4*)(Wd + (kp << 10) + (t << 2));
            half2_ h0 = u2h(h2s[0][kp]);
            half2_ h1 = u2h(h2s[1][kp]);
            a0.x = fdot2_(u2h(w.x), h0, a0.x);
            a0.y = fdot2_(u2h(w.y), h0, a0.y);
            a0.z = fdot2_(u2h(w.z), h0, a0.z);
            a0.w = fdot2_(u2h(w.w), h0, a0.w);
            a1.x = fdot2_(u2h(w.x), h1, a1.x);
            a1.y = fdot2_(u2h(w.y), h1, a1.y);
            a1.z = fdot2_(u2h(w.z), h1, a1.z);
            a1.w = fdot2_(u2h(w.w), h1, a1.w);
        }
        *(float4*)&gbuf[0][t << 2] = a0;
        *(float4*)&gbuf[1][t << 2] = a1;
        __syncthreads();
#pragma unroll
        for (int r = 0; r < 2; r++) {
            float ig = sigmoidf_(gbuf[r][t]);
            float fg = sigmoidf_(gbuf[r][H_ + t]);
            float gg = tanhf(gbuf[r][2 * H_ + t]);
            float og = sigmoidf_(gbuf[r][3 * H_ + t]);
            float c = r ? c1 : c0;
            c = fg * c + ig * gg;
            if (r) c1 = c; else c0 = c;
            float h = og * tanhf(c);
            hf[r][t] = h;
            hs[(size_t)(l * B_ + b0 + r) * 512 + dir * H_ + t] = h;
        }
        __syncthreads();
        // pack h into half2 state for next step's dot2s
        {
            int r = t >> 7, i = t & 127;
            h2s[r][i] = packh2(hf[r][2 * i], hf[r][2 * i + 1]);
        }
        __syncthreads();
    }
}

// ---------------------------------------------------------------------------
// Event head sequential scan. One block (1 wave) per batch row.
__global__ __launch_bounds__(64) void k_event(const float* __restrict__ part,
                                              const float* __restrict__ Wev,
                                              float* __restrict__ out_ev) {
    const int b = blockIdx.x;
    const int e = threadIdx.x;
    __shared__ float sg[33];
    if (e < 33) sg[e] = 0.f;
    float wreg[33];
    if (e < NE_) {
#pragma unroll
        for (int j = 0; j < 33; j++) wreg[j] = Wev[e * 545 + 512 + j];
    }
    __syncthreads();
    for (int l = 0; l < L_; l++) {
        const int m = l * B_ + b;
        float v = -3.0e38f;
        if (e < NE_) {
            v = part[(size_t)m * NCAT_ + 72 + e];
#pragma unroll
            for (int j = 0; j < 33; j++) v += wreg[j] * sg[j];
            out_ev[((size_t)b * L_ + l) * NE_ + e] = v;
        }
        float bv = v;
        int bi = e;
#pragma unroll
        for (int off = 32; off > 0; off >>= 1) {
            float ov = __shfl_xor(bv, off, 64);
            int oi = __shfl_xor(bi, off, 64);
            if (ov > bv || (ov == bv && oi < bi)) { bv = ov; bi = oi; }
        }
        __syncthreads();
        if (bi > 0 && e == bi - 1) sg[e] = 1.f;
        __syncthreads();
    }
}

// ---------------------------------------------------------------------------
// Argument logits broadcast: out[b][i][j][a] = part_i[b][i][a] + part_j[b][j][a]
__global__ __launch_bounds__(256) void k_arg(const float* __restrict__ part,
                                             float* __restrict__ out) {
    const int blk = blockIdx.x;            // b*L_ + i
    const int b = blk >> 7, i = blk & 127;
    __shared__ float pj[L_ * NA_];
    __shared__ float pi_s[NA_];
    const int tid = threadIdx.x;
    if (tid < NA_) pi_s[tid] = part[(size_t)(i * B_ + b) * NCAT_ + 36 + tid];
    for (int idx = tid; idx < L_ * NA_; idx += 256) {
        int j = idx / NA_, a = idx - j * NA_;
        pj[idx] = part[(size_t)(j * B_ + b) * NCAT_ + a];
    }
    __syncthreads();
    float* o = out + (size_t)blk * (L_ * NA_);
    for (int idx = tid; idx < L_ * NA_; idx += 256) {
        int a = idx % NA_;
        o[idx] = pi_s[a] + pj[idx];
    }
}

// ---------------------------------------------------------------------------
extern "C" void kernel_launch(void* const* d_in, const int* in_sizes, int n_in,
                              void* d_out, int out_size, void* d_ws, size_t ws_size,
                              hipStream_t stream) {
    const float* emb  = (const float*)d_in[0];
    const float* Wihf = (const float*)d_in[1];
    const float* Whhf = (const float*)d_in[2];
    const float* bihf = (const float*)d_in[3];
    const float* bhhf = (const float*)d_in[4];
    const float* Wihb = (const float*)d_in[5];
    const float* Whhb = (const float*)d_in[6];
    const float* bihb = (const float*)d_in[7];
    const float* bhhb = (const float*)d_in[8];
    const float* Wev  = (const float*)d_in[9];
    const float* bev  = (const float*)d_in[10];
    const float* Warg = (const float*)d_in[11];
    const float* barg = (const float*)d_in[12];
    const int*   ids  = (const int*)d_in[13];
    float* out = (float*)d_out;
    float* ws  = (float*)d_ws;

    // Workspace layout (floats). X region reused for `part`.
    float*    X       = ws;                 // 8192*304
    float*    part    = ws;                 // 8192*128 (reuse)
    float*    Wt_ih   = ws + 2490368;       // 304*2048
    float*    bias_p  = ws + 3112960;       // 2048
    unsigned* Wp16    = (unsigned*)(ws + 3115008);  // 2*128*1024 uints (262144)
    float*    Wcat    = ws + 3639296;       // 512*128
    float*    bias_c  = ws + 3704832;       // 128
    float*    pre_all = ws + 3704960;       // 8192*2048
    float*    hsbuf   = ws + 20482176;      // 8192*512

    k_gather<<<(M_ * KP_) / 256, 256, 0, stream>>>(emb, ids, X);
    k_prep_wih<<<(KP_ * NPROJ_) / 256, 256, 0, stream>>>(Wihf, Wihb, bihf, bhhf, bihb, bhhb, Wt_ih, bias_p);
    k_prep_whh16<<<(2 * 128 * 1024) / 256, 256, 0, stream>>>(Whhf, Whhb, Wp16);
    k_prep_wcat<<<(K2_ * NCAT_) / 256, 256, 0, stream>>>(Warg, Wev, barg, bev, Wcat, bias_c);

    k_gemm<KP_><<<dim3(M_ / 64, NPROJ_ / 64), 256, 0, stream>>>(X, Wt_ih, bias_p, pre_all, NPROJ_);
    k_lstm3<<<64, 256, 0, stream>>>(pre_all, Wp16, hsbuf);
    k_gemm<K2_><<<dim3(M_ / 64, NCAT_ / 64), 256, 0, stream>>>(hsbuf, Wcat, bias_c, part, NCAT_);
    k_event<<<B_, 64, 0, stream>>>(part, Wev, out);
    k_arg<<<B_ * L_, 256, 0, stream>>>(part, out + (size_t)B_ * L_ * NE_);
}